// Round 1
// 820.665 us; speedup vs baseline: 1.0827x; 1.0827x over previous
//
#include <hip/hip_runtime.h>

#define BB 512
#define TT 1024
#define DX 32
#define DZ 64
#define DY 256
#define ALPHA 0.125f
#define HP 36  // hid_s chunk stride: 32 floats + 4 pad so 8 chunk-readers hit disjoint bank groups

// DPP add: x + dpp_permuted(x), VALU pipe only.
// 0xB1 = quad_perm xor1, 0x4E = quad_perm xor2,
// 0x141 = row_half_mirror (lane -> 7-lane within each 8; after xor1+xor2 this
//         completes an 8-lane allreduce since all quad lanes already hold the quad sum).
template<int CTRL>
__device__ __forceinline__ float dpp_add(float x) {
    int p = __builtin_amdgcn_update_dpp(0, __float_as_int(x), CTRL, 0xF, 0xF, true);
    return x + __int_as_float(p);
}

// One block per batch element, 512 threads (8 waves), 2 blocks/CU (needs <=128 VGPR).
// m1: thread (y=tid>>1, half=tid&1): hidden row y over z-chunk 32*half..+31;
//     1-level DPP (xor1) completes the 64-z dot. Wave w writes hid chunk w.
// m2: thread (z=tid>>3, oct=tid&7): latent row z over y-chunk 32*oct..+31;
//     3-level DPP (xor1,xor2,half_mirror) completes the 256-y dot in-lane.
//     oct==0 lane fuses the state update (A*zf + dot + h1, teacher forcing,
//     output store) -- no partial buffer, no serial wave-0 phase.
// 2 barriers/step (was 3 + wave0-serial phase).
__global__ __launch_bounds__(512, 4)
void plrnn_scan(const float* __restrict__ X, const float* __restrict__ A,
                const float* __restrict__ W1, const float* __restrict__ W2,
                const float* __restrict__ h1, const float* __restrict__ h2,
                float* __restrict__ out) {
    const int b   = blockIdx.x;
    const int tid = threadIdx.x;

    const int y    = tid >> 1;      // m1 output row 0..255
    const int half = tid & 1;       // m1 z-chunk
    const int z    = tid >> 3;      // m2 output row 0..63
    const int oct  = tid & 7;       // m2 y-chunk
    const int wv   = tid >> 6;      // wave id 0..7

    __shared__ float zf_s[DZ];
    __shared__ float hid_s[8 * HP];

    // ---- one-time: weight tiles into registers (32 + 32 floats/thread) ----
    float4 w2r[8];   // W2[y, 32*half + 4j .. +3]
    float4 w1r[8];   // W1[z, 32*oct  + 4j .. +3]
#pragma unroll
    for (int j = 0; j < 8; ++j) {
        w2r[j] = *(const float4*)&W2[y * DZ + 32 * half + 4 * j];
        w1r[j] = *(const float4*)&W1[z * DY + 32 * oct + 4 * j];
    }
    const float h2r = h2[y];   // consumed by half==0 lanes
    const float Ar  = A[z];    // consumed by oct==0 lanes
    const float h1r = h1[z];

    const float* Xb = X   + (size_t)b * TT * DX;
    float*       Ob = out + (size_t)b * TT * DX;

    // ---- zf_0: tf(zeros, X0, 1.0) then tf(z0, X0, 0.125) == x0 (non-NaN) ----
    float zfreg = 0.0f;
    if (oct == 0) {
        float zf = 0.0f;
        if (z < DX) { float x0 = Xb[z]; zf = (x0 == x0) ? x0 : 0.0f; }
        zfreg = zf;
        zf_s[z] = zf;
    }
    __syncthreads();

    const int hidx = wv * HP + (y & 31);   // m1 write slot (half==0 lanes)
    const float* w2f = (const float*)w2r;
    const float* w1f = (const float*)w1r;

    for (int t = 0; t < TT; ++t) {
        // prefetch next forcing value (consumed at the m2 tail)
        float xnext = 0.0f;
        if (oct == 0 && z < DX && (t + 1) < TT) xnext = Xb[(t + 1) * DX + z];

        // ---- m1: hidden = relu(W2 @ zf + h2) ----
        const float4* zp = (const float4*)(zf_s + 32 * half);
        float a0 = 0.f, a1 = 0.f, a2 = 0.f, a3 = 0.f;
#pragma unroll
        for (int j = 0; j < 8; ++j) {
            float4 v = zp[j];
            a0 = fmaf(w2f[4 * j + 0], v.x, a0);
            a1 = fmaf(w2f[4 * j + 1], v.y, a1);
            a2 = fmaf(w2f[4 * j + 2], v.z, a2);
            a3 = fmaf(w2f[4 * j + 3], v.w, a3);
        }
        float d1 = (a0 + a1) + (a2 + a3);
        d1 = dpp_add<0xB1>(d1);                       // + lane^1 -> full 64-z dot
        if (half == 0) hid_s[hidx] = fmaxf(d1 + h2r, 0.0f);
        __syncthreads();

        // ---- m2 + fused update: z_new = A*zf + W1 @ hidden + h1 ----
        const float4* hp = (const float4*)(hid_s + HP * oct);
        float p0 = 0.f, p1 = 0.f, p2 = 0.f, p3 = 0.f;
#pragma unroll
        for (int j = 0; j < 8; ++j) {
            float4 v = hp[j];
            p0 = fmaf(w1f[4 * j + 0], v.x, p0);
            p1 = fmaf(w1f[4 * j + 1], v.y, p1);
            p2 = fmaf(w1f[4 * j + 2], v.z, p2);
            p3 = fmaf(w1f[4 * j + 3], v.w, p3);
        }
        float d2 = (p0 + p1) + (p2 + p3);
        d2 = dpp_add<0xB1>(d2);
        d2 = dpp_add<0x4E>(d2);
        d2 = dpp_add<0x141>(d2);                      // full 256-y dot in all 8 lanes
        if (oct == 0) {
            float znew = fmaf(Ar, zfreg, d2 + h1r);
            float zf = znew;
            if (z < DX) {
                Ob[t * DX + z] = znew;
                zf = (xnext == xnext) ? fmaf(ALPHA, xnext, (1.0f - ALPHA) * znew)
                                      : znew;
            }
            zfreg = zf;
            zf_s[z] = zf;
        }
        __syncthreads();
    }
}

extern "C" void kernel_launch(void* const* d_in, const int* in_sizes, int n_in,
                              void* d_out, int out_size, void* d_ws, size_t ws_size,
                              hipStream_t stream) {
    const float* X  = (const float*)d_in[0];
    const float* A  = (const float*)d_in[1];
    const float* W1 = (const float*)d_in[2];
    const float* W2 = (const float*)d_in[3];
    const float* h1 = (const float*)d_in[4];
    const float* h2 = (const float*)d_in[5];
    float* out = (float*)d_out;

    plrnn_scan<<<BB, 512, 0, stream>>>(X, A, W1, W2, h1, h2, out);
}